// Round 17
// baseline (933.253 us; speedup 1.0000x reference)
//
#include <hip/hip_runtime.h>
#include <hip/hip_bf16.h>
#include <math.h>

#define B_ 8
#define L_ 512
#define DV_ 512
#define DM_ 512
#define PL_ 96
#define EL_ 3
#define DS_ 16
#define DC_ 4
#define DI_ 1024
#define DTR_ 32
#define S_ 512
#define M_ 4096        // B*S
#define CH_ 16         // scan chunks
#define CS_ 32         // steps per chunk
#define LOG2E_ 1.44269504088896f

typedef float f32x4 __attribute__((ext_vector_type(4)));
typedef short bf16x8 __attribute__((ext_vector_type(8)));
typedef short bf16x4 __attribute__((ext_vector_type(4)));

__device__ __forceinline__ float bf2f(short s) {
  unsigned u = ((unsigned)(unsigned short)s) << 16;
  return __builtin_bit_cast(float, u);
}
__device__ __forceinline__ short f2bf(float f) {
  unsigned u = __builtin_bit_cast(unsigned, f);
  u = u + 0x7FFFu + ((u >> 16) & 1u);   // RNE
  return (short)(u >> 16);
}
__device__ __forceinline__ float h2f(unsigned short u) {
  _Float16 h = __builtin_bit_cast(_Float16, u);
  return (float)h;
}
__device__ __forceinline__ unsigned short f2h(float f) {
  _Float16 h = (_Float16)f;
  return __builtin_bit_cast(unsigned short, h);
}

// Native v_exp_f32 (exp2).  NOT libm exp2f (denormal fixups — round-7
// regression).  Fallback keeps correctness if the builtin is missing.
__device__ __forceinline__ float exp2n(float x) {
#if __has_builtin(__builtin_amdgcn_exp2f)
  return __builtin_amdgcn_exp2f(x);
#else
  return __expf(x * 0.69314718055994531f);
#endif
}

// global -> LDS DMA, 16B per lane.  LDS dest is wave-uniform base + lane*16.
__device__ __forceinline__ void gload16(const short* g, short* l) {
  __builtin_amdgcn_global_load_lds(
      (const __attribute__((address_space(1))) void*)g,
      (__attribute__((address_space(3))) void*)l, 16, 0, 0);
}

// ---------------------------------------------------------------------------
// One-shot fp32 -> bf16 conversion of ALL GEMM weights into workspace.
// ---------------------------------------------------------------------------
#define WC0 65536                 // emb_w      512*512
#define WC1 (WC0 + 1572864)       // m_in_w     6*2048*512
#define WC2 (WC1 + 98304)         // m_xp_w     6*64*1024
#define WC3 (WC2 + 49152)         // m_dt_w     6*1024*32
#define WC4 (WC3 + 786432)        // m_out_w    6*512*1024
#define WC5 (WC4 + 786432)        // ffn_w1     3*2048*512
#define WC6 (WC5 + 786432)        // ffn_w2     3*512*2048
#define WC7 (WC6 + 12288)        // proj_w     96*512
// WC7 = 4157440 float4s; grid = 16240 * 256 exactly.

__global__ __launch_bounds__(256)
void wcvt_k(const float* __restrict__ e, const float* __restrict__ iw,
            const float* __restrict__ xp, const float* __restrict__ dtw,
            const float* __restrict__ ow, const float* __restrict__ w1,
            const float* __restrict__ w2, const float* __restrict__ pw,
            short* __restrict__ de, short* __restrict__ di,
            short* __restrict__ dxp, short* __restrict__ ddt,
            short* __restrict__ dow, short* __restrict__ dw1,
            short* __restrict__ dw2, short* __restrict__ dpw)
{
  int idx = blockIdx.x * 256 + threadIdx.x;
  const float* s; short* d; int off;
  if (idx < WC0)      { s = e;   d = de;  off = idx; }
  else if (idx < WC1) { s = iw;  d = di;  off = idx - WC0; }
  else if (idx < WC2) { s = xp;  d = dxp; off = idx - WC1; }
  else if (idx < WC3) { s = dtw; d = ddt; off = idx - WC2; }
  else if (idx < WC4) { s = ow;  d = dow; off = idx - WC3; }
  else if (idx < WC5) { s = w1;  d = dw1; off = idx - WC4; }
  else if (idx < WC6) { s = w2;  d = dw2; off = idx - WC5; }
  else                { s = pw;  d = dpw; off = idx - WC6; }
  float4 v = ((const float4*)s)[off];
  union { short sh[4]; int2 p; } r;
  r.sh[0] = f2bf(v.x); r.sh[1] = f2bf(v.y);
  r.sh[2] = f2bf(v.z); r.sh[3] = f2bf(v.w);
  ((int2*)d)[off] = r.p;
}

// ---------------------------------------------------------------------------
// Instance-norm statistics, two-phase.
// ---------------------------------------------------------------------------
__global__ __launch_bounds__(256)
void stats1_k(const float* __restrict__ x, float* __restrict__ ps)
{
  int d = blockIdx.x * 256 + threadIdx.x;       // 0..511
  int b = blockIdx.y;
  int lc = blockIdx.z;                          // 16 chunks of 32
  const float* xp = x + ((size_t)b * L_ + lc * 32) * DV_ + d;
  float s = 0.f, ss = 0.f;
  #pragma unroll 8
  for (int l = 0; l < 32; l++) {
    float v = xp[(size_t)l * DV_];
    s += v; ss += v * v;
  }
  int o = (lc * B_ + b) * DV_ + d;
  ps[o] = s; ps[o + 16 * B_ * DV_] = ss;
}

__global__ __launch_bounds__(256)
void stats2_k(const float* __restrict__ x, const float* __restrict__ ps,
              float* __restrict__ means, float* __restrict__ stdev,
              float* __restrict__ rstd, float* __restrict__ xlast)
{
  int d = blockIdx.x * 256 + threadIdx.x;
  int b = blockIdx.y;
  float s = 0.f, ss = 0.f;
  #pragma unroll
  for (int lc = 0; lc < 16; lc++) {
    int o = (lc * B_ + b) * DV_ + d;
    s += ps[o]; ss += ps[o + 16 * B_ * DV_];
  }
  float mu = s / (float)L_;
  float var = ss / (float)L_ - mu * mu;
  float sd = sqrtf(var + 1e-5f);
  float rs = 1.f / sd;
  int idx = b * DV_ + d;
  means[idx] = mu; stdev[idx] = sd; rstd[idx] = rs;
  xlast[idx] = (x[((size_t)b * L_ + L_ - 1) * DV_ + d] - mu) * rs;
}

// ---------------------------------------------------------------------------
// Normalize + transpose: xnT[b,d,l] = (x[b,l,d]-mu[b,d])*rstd[b,d]  (bf16)
// ---------------------------------------------------------------------------
__global__ __launch_bounds__(256)
void tnorm_k(const float* __restrict__ x, const float* __restrict__ means,
             const float* __restrict__ rstd, short* __restrict__ xnT)
{
  __shared__ float tile[64][65];
  const int t = threadIdx.x;
  const int j = t & 63;
  const int i0 = t >> 6;                 // 0..3
  const int bz = blockIdx.z;
  const int l0 = blockIdx.y << 6;
  const int d0 = blockIdx.x << 6;
  const float* xp = x + ((size_t)bz * L_ + l0) * DV_ + d0;
  #pragma unroll
  for (int i = i0; i < 64; i += 4) tile[i][j] = xp[(size_t)i * DV_ + j];
  __syncthreads();
  short* op = xnT + ((size_t)bz * DV_ + d0) * L_ + l0;
  const int sb = bz * DV_ + d0;
  #pragma unroll
  for (int i = i0; i < 64; i += 4) {
    float mu = means[sb + i];
    float rs = rstd[sb + i];
    op[(size_t)i * L_ + j] = f2bf((tile[j][i] - mu) * rs);
  }
}

// ---------------------------------------------------------------------------
// Fused LayerNorm: optionally h += add (+ abias) in place, then LN -> bf16.
// ---------------------------------------------------------------------------
template <int ADD>
__global__ __launch_bounds__(256)
void ln_k(float* __restrict__ X, const short* __restrict__ add,
          const float* __restrict__ abias,
          const float* __restrict__ g, const float* __restrict__ b,
          short* __restrict__ Y)
{
  int row = blockIdx.x;
  float* x = X + (size_t)row * DM_;
  int t = threadIdx.x;
  float v0 = x[t], v1 = x[t + 256];
  if constexpr (ADD >= 1) {
    v0 += bf2f(add[(size_t)row * DM_ + t]);
    v1 += bf2f(add[(size_t)row * DM_ + t + 256]);
    if constexpr (ADD == 2) { v0 += abias[t]; v1 += abias[t + 256]; }
    x[t] = v0; x[t + 256] = v1;
  }
  float s = v0 + v1, ss = v0 * v0 + v1 * v1;
  #pragma unroll
  for (int o = 1; o < 64; o <<= 1) { s += __shfl_xor(s, o); ss += __shfl_xor(ss, o); }
  __shared__ float sb[8];
  int wave = t >> 6, lane = t & 63;
  if (lane == 0) { sb[wave] = s; sb[4 + wave] = ss; }
  __syncthreads();
  s = sb[0] + sb[1] + sb[2] + sb[3];
  ss = sb[4] + sb[5] + sb[6] + sb[7];
  float mu = s / (float)DM_;
  float var = ss / (float)DM_ - mu * mu;
  float rs = rsqrtf(var + 1e-5f);
  Y[(size_t)row * DM_ + t]       = f2bf((v0 - mu) * rs * g[t]       + b[t]);
  Y[(size_t)row * DM_ + t + 256] = f2bf((v1 - mu) * rs * g[t + 256] + b[t + 256]);
}

// ---------------------------------------------------------------------------
// Depthwise causal conv, BOTH DIRS in one dispatch.  Vectorized, 8 ch/thread.
// ---------------------------------------------------------------------------
__global__ __launch_bounds__(256)
void conv2_k(const short* __restrict__ xcin, const float* __restrict__ w0,
             const float* __restrict__ w1, const float* __restrict__ cb0,
             const float* __restrict__ cb1, short* __restrict__ xcout)
{
  int idx = blockIdx.x * 256 + threadIdx.x;   // over 2*B*S*DI/8 = 2^20
  int dir = idx >> 19;
  int id2 = idx & ((1 << 19) - 1);
  int ig = (id2 & 127) << 3;                  // channel group base
  int bs = id2 >> 7;                          // b*S + tau
  int tt0 = bs & (S_ - 1);
  int b = bs >> 9;
  const float* w  = dir ? w1  : w0;
  const float* cb = dir ? cb1 : cb0;
  const short* u = xcin + (size_t)dir * M_ * DI_ + (size_t)(b * S_) * DI_ + ig;
  float4 wv[8];
  #pragma unroll
  for (int n = 0; n < 8; n++) wv[n] = *(const float4*)(w + (ig + n) * DC_);
  float acc[8];
  {
    float4 c0 = *(const float4*)(cb + ig);
    float4 c1 = *(const float4*)(cb + ig + 4);
    acc[0] = c0.x; acc[1] = c0.y; acc[2] = c0.z; acc[3] = c0.w;
    acc[4] = c1.x; acc[5] = c1.y; acc[6] = c1.z; acc[7] = c1.w;
  }
  #pragma unroll
  for (int k = 0; k < DC_; k++) {
    int tt = tt0 - (DC_ - 1) + k;
    if (tt >= 0) {
      bf16x8 uv = *(const bf16x8*)(u + (size_t)tt * DI_);
      #pragma unroll
      for (int n = 0; n < 8; n++) {
        float wk = (k == 0) ? wv[n].x : (k == 1) ? wv[n].y
                 : (k == 2) ? wv[n].z : wv[n].w;
        acc[n] += wk * bf2f(uv[n]);
      }
    }
  }
  union { short sh[8]; bf16x8 v; } r;
  #pragma unroll
  for (int n = 0; n < 8; n++) {
    float sig = 1.f / (1.f + __expf(-acc[n]));
    r.sh[n] = f2bf(acc[n] * sig);
  }
  *(bf16x8*)(xcout + (size_t)dir * M_ * DI_ + ((size_t)bs << 10) + ig) = r.v;
}

// ---------------------------------------------------------------------------
// Chunked selective scan, both dirs fused, forward-only, LDS-staged,
// B/C pre-converted to fp32 in LDS (round-15 proven config — unchanged).
// ---------------------------------------------------------------------------
__global__ __launch_bounds__(256)
void scan_p1(const unsigned short* __restrict__ dt16, const short* __restrict__ xc,
             const short* __restrict__ xdbl, const float* __restrict__ A_log,
             unsigned short* __restrict__ part_h, unsigned short* __restrict__ part_A)
{
  __shared__ short ldt[CS_ * 64];   // [32][64] fp16 dt
  __shared__ short lu [CS_ * 64];   // [32][64] bf16 u
  __shared__ short lb [CS_ * 16];   // [32][16] bf16 B (staging)
  __shared__ __align__(16) float lbf[CS_ * 16];   // [32][16] fp32 B
  const int tid = threadIdx.x;
  const int bid = blockIdx.x;                 // 0..255
  const int c = blockIdx.y;
  const int q = tid & 3;
  const int il = tid >> 2;                    // 0..63
  const int i = ((bid & 15) << 6) + il;
  const int b = (bid >> 4) & (B_ - 1);
  const int dir = bid >> 7;

  {  // stage: dt,u rows [32][64] (16B/thread each); B rows [32][16] (wave 0)
    const int srow = tid >> 3, scol = (tid & 7) << 3;
    const size_t g = (size_t)dir * M_ * DI_ +
                     ((size_t)b * S_ + c * CS_ + srow) * DI_ + ((bid & 15) << 6) + scol;
    const int wb = (tid >> 6) << 9;           // wave*512 shorts
    gload16((const short*)dt16 + g, &ldt[wb]);
    gload16(xc + g, &lu[wb]);
    if (tid < 64) {
      const int brow = tid >> 1, bcol = (tid & 1) << 3;
      const size_t gb = (size_t)dir * M_ * 64 +
                        ((size_t)b * S_ + c * CS_ + brow) * 64 + DTR_ + bcol;
      gload16(xdbl + gb, &lb[0]);
    }
  }
  asm volatile("s_waitcnt vmcnt(0)" ::: "memory");
  __builtin_amdgcn_s_barrier();
  // one-shot B convert: 512 values, 2/thread
  lbf[tid] = bf2f(lb[tid]);
  lbf[tid + 256] = bf2f(lb[tid + 256]);
  __syncthreads();

  float Ai2[4];
  const float* al = A_log + (size_t)dir * DI_ * DS_ + i * DS_ + q * 4;
  #pragma unroll
  for (int n = 0; n < 4; n++) Ai2[n] = -__expf(al[n]) * LOG2E_;

  float h[4];
  #pragma unroll
  for (int n = 0; n < 4; n++) h[n] = 0.f;
  float dsum = 0.f;

  const unsigned short* pdt = (const unsigned short*)ldt + il;
  const short* pu = lu + il;
  const float* pb = lbf + q * 4;
  for (int s0 = 0; s0 < CS_; s0 += 8) {
    #pragma unroll
    for (int k = 0; k < 8; k++) {
      float dtv = h2f(pdt[k * 64]);
      float u = bf2f(pu[k * 64]);
      f32x4 vB = *(const f32x4*)(pb + k * 16);
      float du = dtv * u;
      dsum += dtv;
      #pragma unroll
      for (int n = 0; n < 4; n++) {
        float dA = exp2n(dtv * Ai2[n]);
        h[n] = dA * h[n] + du * vB[n];
      }
    }
    pdt += 512; pu += 512; pb += 128;
  }
  union { unsigned short s[4]; int2 v; } uh, ua;
  #pragma unroll
  for (int n = 0; n < 4; n++) {
    uh.s[n] = f2h(h[n]);
    ua.s[n] = f2h(exp2n(Ai2[n] * dsum));   // exact: prod exp(dt*A)=exp(A*sum dt)
  }
  const size_t ix = ((((size_t)c * 2 * B_ + dir * B_ + b) * DI_ + i) << 4) + (q << 2);
  *(int2*)(part_h + ix) = uh.v;
  *(int2*)(part_A + ix) = ua.v;
}

__global__ __launch_bounds__(256)
void scan_p2(unsigned short* __restrict__ part_h,
             const unsigned short* __restrict__ part_A)
{
  const size_t gid = (size_t)blockIdx.x * 256 + threadIdx.x;   // 2*B*DI*DS
  const size_t stride = (size_t)2 * B_ * DI_ * DS_;
  float hin = 0.f;
  #pragma unroll
  for (int c = 0; c < CH_; c++) {
    size_t ix = (size_t)c * stride + gid;
    float hh = h2f(part_h[ix]);
    float pA = h2f(part_A[ix]);
    part_h[ix] = f2h(hin);            // becomes chunk c's incoming state
    hin = hh + pA * hin;
  }
}

// y overwrites dt16 in place; reads come from the LDS snapshot staged
// before any store, so there is no RAW hazard at all.
__global__ __launch_bounds__(256)
void scan_p3(unsigned short* dt16, const short* __restrict__ xc,
             const short* __restrict__ xdbl, const short* __restrict__ zb,
             const float* __restrict__ A_log, const float* __restrict__ Dp,
             const unsigned short* __restrict__ part_h)
{
  __shared__ short ldt[CS_ * 64];   // [32][64] fp16 dt
  __shared__ short lu [CS_ * 64];   // [32][64] bf16 u
  __shared__ short lz [CS_ * 64];   // [32][64] bf16 silu(z)
  __shared__ short lbc[CS_ * 32];   // [32][32] bf16 B|C (staging)
  __shared__ __align__(16) float lbcf[CS_ * 32];  // [32][32] fp32 B|C
  const int tid = threadIdx.x;
  const int bid = blockIdx.x;
  const int c = blockIdx.y;
  const int q = tid & 3;
  const int il = tid >> 2;
  const int i = ((bid & 15) << 6) + il;
  const int b = (bid >> 4) & (B_ - 1);
  const int dir = bid >> 7;

  const size_t base = (size_t)dir * M_ * DI_ +
                      ((size_t)b * S_ + c * CS_) * DI_ + ((bid & 15) << 6);
  {  // stage: dt,u,z rows [32][64]; B|C rows [32][32] (waves 0-1)
    const int srow = tid >> 3, scol = (tid & 7) << 3;
    const size_t g = base + (size_t)srow * DI_ + scol;
    const int wb = (tid >> 6) << 9;
    gload16((const short*)dt16 + g, &ldt[wb]);
    gload16(xc + g, &lu[wb]);
    gload16(zb + g, &lz[wb]);
    if (tid < 128) {
      const int brow = tid >> 2, bcol = (tid & 3) << 3;
      const size_t gb = (size_t)dir * M_ * 64 +
                        ((size_t)b * S_ + c * CS_ + brow) * 64 + DTR_ + bcol;
      gload16(xdbl + gb, &lbc[(tid >> 6) << 9]);
    }
  }
  asm volatile("s_waitcnt vmcnt(0)" ::: "memory");
  __builtin_amdgcn_s_barrier();
  // one-shot B|C convert: 1024 values, 4/thread
  #pragma unroll
  for (int p = 0; p < 4; p++)
    lbcf[p * 256 + tid] = bf2f(lbc[p * 256 + tid]);
  __syncthreads();

  float Ai2[4];
  const float* al = A_log + (size_t)dir * DI_ * DS_ + i * DS_ + q * 4;
  #pragma unroll
  for (int n = 0; n < 4; n++) Ai2[n] = -__expf(al[n]) * LOG2E_;
  const float Di = Dp[(size_t)dir * DI_ + i];

  float h[4];
  {
    const size_t ix = ((((size_t)c * 2 * B_ + dir * B_ + b) * DI_ + i) << 4) + (q << 2);
    union { unsigned short s[4]; int2 v; } uh;
    uh.v = *(const int2*)(part_h + ix);
    #pragma unroll
    for (int n = 0; n < 4; n++) h[n] = h2f(uh.s[n]);
  }

  const unsigned short* pdt = (const unsigned short*)ldt + il;
  const short* pu = lu + il;
  const short* pz = lz + il;
  const float* pbc = lbcf + q * 4;
  short* py = (short*)dt16 + base + il;       // y over dt (global)

  for (int s0 = 0; s0 < CS_; s0 += 4) {
    #pragma unroll
    for (int k = 0; k < 4; k++) {
      float dtv = h2f(pdt[k * 64]);
      float u = bf2f(pu[k * 64]);
      float sil = bf2f(pz[k * 64]);
      f32x4 vB = *(const f32x4*)(pbc + k * 32);
      f32x4 vC = *(const f32x4*)(pbc + k * 32 + 16);
      float du = dtv * u;
      float yp = 0.f;
      #pragma unroll
      for (int n = 0; n < 4; n++) {
        float dA = exp2n(dtv * Ai2[n]);
        h[n] = dA * h[n] + du * vB[n];
        yp += h[n] * vC[n];
      }
      yp += __shfl_xor(yp, 1);
      yp += __shfl_xor(yp, 2);          // quad-wide sum over all 16 states
      float yv = (yp + u * Di) * sil;
      if (q == 0) py[(size_t)k * DI_] = f2bf(yv);
    }
    pdt += 256; pu += 256; pz += 256; pbc += 128; py += 4 * DI_;
  }
}

// ---------------------------------------------------------------------------
// bf16 MFMA GEMM.  Round 17: the XOR swizzle now uses the ROW PAIR
// ((r>>1) & MSK) instead of (r & MSK).  At BK=32 a row is only 4 16B
// chunks (64B = 16 banks), so the old per-row XOR left each 16-lane read
// phase on 4 bank-starts x 4 lanes = 4-way conflict (measured 3.15M
// SQ_LDS_BANK_CONFLICT on the 64x128xBK32 dispatches).  Pair-swizzle
// spreads it to 8 starts x 2 lanes (2-way = free); BK=64 stays 2-way-free
// (enumerated).  Applied identically to DMA-source offsets and MFMA-side
// reads (rule #21: same involution both sides).
// ---------------------------------------------------------------------------
enum { EPI_F32_BIAS, EPI_BF16, EPI_F16_SOFTPLUS, EPI_HALF_BF16, EPI_GELU,
       EPI_PROJ, EPI_INPROJ2 };

template <int EPI, int BM, int BN, int BK, int REVA = 0>
__global__ __launch_bounds__(256)
void gemm_k(const short* __restrict__ A0, const short* __restrict__ A1,
            const short* __restrict__ W0, const short* __restrict__ W1,
            int khalf, int mhalf, int N, int K, int lda, int ldw,
            float* __restrict__ Cf, short* __restrict__ Cb, int ldc,
            const float* __restrict__ bias,
            const float* __restrict__ xlast, const float* __restrict__ stdev,
            const float* __restrict__ means)
{
  constexpr int MT = BM / 32;
  constexpr int NT = BN / 32;
  constexpr int KS = BK / 32;
  constexpr int CHK = BK / 8;
  constexpr int MSK = CHK - 1;
  constexpr int NA = (BM * CHK) / 256;
  constexpr int NW = (BN * CHK) / 256;
  constexpr int VC = NA + NW;
  __shared__ __align__(16) short As[3][BM * BK];
  __shared__ __align__(16) short Ws[3][BN * BK];
  const int tid = threadIdx.x;
  const int m0 = blockIdx.x * BM;
  const int n0 = blockIdx.y * BN;
  const int wave = tid >> 6, lane = tid & 63;
  const int wm = (wave & 1) * (BM / 2), wn = (wave >> 1) * (BN / 2);
  const int quad = lane >> 4, l16 = lane & 15;

  const short* W0m = (m0 < mhalf) ? W0 : W1;   // block-uniform M-half switch

  f32x4 acc[MT][NT] = {};

  size_t aoff[NA], aoffR[REVA ? NA : 1];
  #pragma unroll
  for (int j = 0; j < NA; j++) {
    int id = j * 256 + tid;
    int r = id / CHK, qp = id % CHK;
    aoff[j] = (size_t)(m0 + r) * lda + ((qp ^ ((r >> 1) & MSK)) << 3);
    if constexpr (REVA)
      aoffR[j] = (size_t)((m0 + r) ^ (S_ - 1)) * lda + ((qp ^ ((r >> 1) & MSK)) << 3);
  }
  size_t woff[NW];
  #pragma unroll
  for (int j = 0; j < NW; j++) {
    int id = j * 256 + tid;
    int r = id / CHK, qp = id % CHK;
    int wr = n0 + r; if (wr > N - 1) wr = N - 1;
    woff[j] = (size_t)wr * ldw + ((qp ^ ((r >> 1) & MSK)) << 3);
  }
  const int lbase = wave * 512;

  const int KB = K / BK;

  auto stage = [&](int slab, int bi) {
    const int k0 = slab * BK;
    const short* Ab = (k0 < khalf) ? A0 + k0 : A1 + (k0 - khalf);
    const short* Wb = (k0 < khalf) ? W0m + k0 : W1 + (k0 - khalf);
    const size_t* ao = (REVA && k0 >= khalf) ? aoffR : aoff;
    #pragma unroll
    for (int j = 0; j < NA; j++)
      gload16(Ab + ao[j], &As[bi][j * 2048 + lbase]);
    #pragma unroll
    for (int j = 0; j < NW; j++)
      gload16(Wb + woff[j], &Ws[bi][j * 2048 + lbase]);
  };

  stage(0, 0);
  if (KB > 1) stage(1, 1);
  __builtin_amdgcn_sched_barrier(0);
  if (KB > 1) asm volatile("s_waitcnt vmcnt(%0)" :: "n"(VC) : "memory");
  else        asm volatile("s_waitcnt vmcnt(0)" ::: "memory");
  __builtin_amdgcn_s_barrier();
  __builtin_amdgcn_sched_barrier(0);

  int cur = 0, nxt = 2;
  for (int kb = 0; kb < KB; kb++) {
    if (kb + 2 < KB) {
      stage(kb + 2, nxt);
      __builtin_amdgcn_sched_barrier(0);
    }
    bf16x8 af[MT][KS], bfr[NT][KS];
    #pragma unroll
    for (int mt = 0; mt < MT; mt++)
      #pragma unroll
      for (int st = 0; st < KS; st++)
        af[mt][st] = *(const bf16x8*)(&As[cur][0] + (wm + mt * 16 + l16) * BK +
                                      (((st * 4 + quad) ^ ((l16 >> 1) & MSK)) << 3));
    #pragma unroll
    for (int nt = 0; nt < NT; nt++)
      #pragma unroll
      for (int st = 0; st < KS; st++)
        bfr[nt][st] = *(const bf16x8*)(&Ws[cur][0] + (wn + nt * 16 + l16) * BK +
                                       (((st * 4 + quad) ^ ((l16 >> 1) & MSK)) << 3));
    #pragma unroll
    for (int st = 0; st < KS; st++)
      #pragma unroll
      for (int mt = 0; mt < MT; mt++)
        #pragma unroll
        for (int nt = 0; nt < NT; nt++)
          acc[mt][nt] = __builtin_amdgcn_mfma_f32_16x16x32_bf16(
              af[mt][st], bfr[nt][st], acc[mt][nt], 0, 0, 0);
    if (kb + 1 < KB) {
      __builtin_amdgcn_sched_barrier(0);
      if (kb + 2 < KB) asm volatile("s_waitcnt vmcnt(%0)" :: "n"(VC) : "memory");
      else             asm volatile("s_waitcnt vmcnt(0)" ::: "memory");
      __builtin_amdgcn_s_barrier();
      __builtin_amdgcn_sched_barrier(0);
      cur = (cur == 2) ? 0 : cur + 1;
      nxt = (nxt == 2) ? 0 : nxt + 1;
    }
  }

  const int boff = (m0 < mhalf) ? 0 : N;   // M-half bias switch (contiguous)

  #pragma unroll
  for (int mt = 0; mt < MT; mt++) {
    #pragma unroll
    for (int nt = 0; nt < NT; nt++) {
      int n = n0 + wn + nt * 16 + l16;
      if (n >= N) continue;
      #pragma unroll
      for (int r = 0; r < 4; r++) {
        int m = m0 + wm + mt * 16 + quad * 4 + r;
        float v = acc[mt][nt][r];
        if constexpr (EPI == EPI_F32_BIAS) {
          Cf[(size_t)m * ldc + n] = v + bias[n];
        } else if constexpr (EPI == EPI_BF16) {
          Cb[(size_t)m * ldc + n] = f2bf(v);
        } else if constexpr (EPI == EPI_F16_SOFTPLUS) {
          float tt = v + bias[n + boff];
          float sp = (tt > 20.f) ? tt : log1pf(__expf(tt));
          ((unsigned short*)Cb)[(size_t)m * ldc + n] = f2h(sp);
        } else if constexpr (EPI == EPI_HALF_BF16) {
          Cb[(size_t)m * ldc + n] = f2bf(0.5f * v);
        } else if constexpr (EPI == EPI_GELU) {
          float tt = v + bias[n];
          Cb[(size_t)m * ldc + n] = f2bf(0.5f * tt * (1.f + erff(tt * 0.70710678118f)));
        } else if constexpr (EPI == EPI_PROJ) {
          int bb = m >> 9, d = m & 511;
          float tt = v + bias[n] + xlast[m];
          tt = tt * stdev[m] + means[m];
          Cf[((size_t)bb * PL_ + n) * DV_ + d] = tt;
        } else if constexpr (EPI == EPI_INPROJ2) {
          // fused 2-dir in-proj: dir = n>>11; dir1 rows stored reversed.
          int d2 = n >> 11, nn = n & 2047;
          int mm = d2 ? (m ^ (S_ - 1)) : m;
          short* sc2 = Cb + (size_t)d2 * M_ * DI_;
          short* zb2 = (short*)Cf + (size_t)d2 * M_ * DI_;
          if (nn < DI_) sc2[(size_t)mm * DI_ + nn] = f2bf(v);
          else {
            float sz = v / (1.f + __expf(-v));     // pre-apply silu to z
            zb2[(size_t)mm * DI_ + (nn - DI_)] = f2bf(sz);
          }
        }
      }
    }
  }
}

// ---------------------------------------------------------------------------
extern "C" void kernel_launch(void* const* d_in, const int* in_sizes, int n_in,
                              void* d_out, int out_size, void* d_ws, size_t ws_size,
                              hipStream_t stream)
{
  (void)in_sizes; (void)n_in; (void)out_size; (void)ws_size;
  const float* x        = (const float*)d_in[0];
  const float* emb_w    = (const float*)d_in[1];
  const float* emb_b    = (const float*)d_in[2];
  const float* ln_g     = (const float*)d_in[3];
  const float* ln_b     = (const float*)d_in[4];
  const float* m_in_w   = (const float*)d_in[5];
  const float* m_conv_w = (const float*)d_in[6];
  const float* m_conv_b = (const float*)d_in[7];
  const float* m_xp_w   = (const float*)d_in[8];
  const float* m_dt_w   = (const float*)d_in[9];
  const float* m_dt_b   = (const float*)d_in[10];
  const float* m_A_log  = (const float*)d_in[11];
  const float* m_D      = (const float*)d_in[12];
  const float* m_out_w  = (const float*)d_in[13];
  const float* ffn_ln_g = (const float*)d_in[14];
  const float* ffn_ln_b = (const float*)d_in[15];
  const float* ffn_w1   = (const float*)d_in[16];
  const float* ffn_b1   = (const float*)d_in[17];
  const float* ffn_w2   = (const float*)d_in[18];
  const float* ffn_b2   = (const float*)d_in[19];
  const float* enc_g    = (const float*)d_in[20];
  const float* enc_b    = (const float*)d_in[21];
  const float* proj_w   = (const float*)d_in[22];
  const float* proj_b   = (const float*)d_in[23];
  float* out = (float*)d_out;

  char* ws = (char*)d_ws;
  const size_t MB = 1024 * 1024;
  // Layout (high-water 128 MB):
  //  0-8   h | 8-12 hn | 12-16 ftmp/vtmp | 16-24 part_h (scan window)
  //  8-16  part_A alias | 24-40 zbuf/xnT/f1out | 40-56 xc | 56-72 dtb (y in
  //  place) | 72-73 xdbl | 73 stats(+partials) | 80-112 bf16 weight pool |
  //  112-128 conv scratch [2][M][DI]
  float* h      = (float*)(ws + 0);
  short* hn     = (short*)(ws + 8 * MB);
  short* ftmp   = (short*)(ws + 12 * MB);
  short* vtmp   = ftmp;
  short* zbuf   = (short*)(ws + 24 * MB);
  short* xnT    = zbuf;
  short* f1out  = zbuf;
  short* xc     = (short*)(ws + 40 * MB);
  unsigned short* dtb = (unsigned short*)(ws + 56 * MB);
  short* xdbl   = (short*)(ws + 72 * MB);
  float* stats  = (float*)(ws + 73 * MB);
  unsigned short* part_A = (unsigned short*)(ws + 8 * MB);
  unsigned short* part_h = (unsigned short*)(ws + 16 * MB);
  short* scratch= (short*)(ws + 112 * MB);   // [2][M][DI] conv input
  float* means = stats, *stdevp = stats + 4096, *rstd = stats + 8192, *xlast = stats + 12288;
  float* pstat = stats + 16384;              // 16x8x512 x2 partials (512KB)

  short* emb_wb = (short*)(ws + 80 * MB);
  short* in_wb  = emb_wb + 262144;      // 6 x 2048x512
  short* xp_wb  = in_wb  + 6291456;     // 6 x 64x1024
  short* dt_wb  = xp_wb  + 393216;      // 6 x 1024x32
  short* out_wb = dt_wb  + 196608;      // 6 x 512x1024
  short* w1b    = out_wb + 3145728;     // 3 x 2048x512
  short* w2b    = w1b    + 3145728;     // 3 x 512x2048
  short* projb  = w2b    + 3145728;     // 96x512

  dim3 blk(256);
  const int NOSPLIT = 1 << 30;

  wcvt_k<<<dim3(16240), blk, 0, stream>>>(
      emb_w, m_in_w, m_xp_w, m_dt_w, m_out_w, ffn_w1, ffn_w2, proj_w,
      emb_wb, in_wb, xp_wb, dt_wb, out_wb, w1b, w2b, projb);

  stats1_k<<<dim3(2, B_, 16), blk, 0, stream>>>(x, pstat);
  stats2_k<<<dim3(2, B_), blk, 0, stream>>>(x, pstat, means, stdevp, rstd, xlast);
  tnorm_k<<<dim3(8, 8, B_), blk, 0, stream>>>(x, means, rstd, xnT);
  // emb: M=4096, N=512, K=512
  gemm_k<EPI_F32_BIAS, 64, 32, 64><<<dim3(64, 16), blk, 0, stream>>>(
      xnT, xnT, emb_wb, emb_wb, NOSPLIT, NOSPLIT, DM_, L_, L_, L_,
      h, nullptr, DM_, emb_b, nullptr, nullptr, nullptr);

  for (int il = 0; il < EL_; il++) {
    if (il == 0)
      ln_k<0><<<dim3(4096), blk, 0, stream>>>(h, nullptr, nullptr, ln_g, ln_b, hn);
    else
      ln_k<2><<<dim3(4096), blk, 0, stream>>>(h, ftmp, ffn_b2 + (il - 1) * DM_,
          ln_g + il * DM_, ln_b + il * DM_, hn);
    // in-proj BOTH DIRS fused: N=4096, K=512 — grid (64, 32) = 2048 blocks
    gemm_k<EPI_INPROJ2, 64, 128, 32><<<dim3(64, 32), blk, 0, stream>>>(
        hn, hn, in_wb + (size_t)(2 * il) * 2 * DI_ * DM_,
        in_wb + (size_t)(2 * il) * 2 * DI_ * DM_, NOSPLIT, NOSPLIT,
        4 * DI_, DM_, DM_, DM_,
        (float*)zbuf, scratch, DI_, nullptr, nullptr, nullptr, nullptr);
    // conv BOTH DIRS fused: grid 4096
    conv2_k<<<dim3(4096), blk, 0, stream>>>(
        scratch, m_conv_w + (size_t)(2 * il) * DI_ * DC_,
        m_conv_w + (size_t)(2 * il + 1) * DI_ * DC_,
        m_conv_b + (size_t)(2 * il) * DI_,
        m_conv_b + (size_t)(2 * il + 1) * DI_, xc);
    // xdbl (both dirs): M=8192, N=64, K=1024; W switches at m=4096
    gemm_k<EPI_BF16, 32, 32, 64><<<dim3(256, 2), blk, 0, stream>>>(
        xc, xc, xp_wb + (size_t)(2 * il) * 64 * DI_,
        xp_wb + (size_t)(2 * il + 1) * 64 * DI_, NOSPLIT, M_,
        64, DI_, DI_, DI_,
        nullptr, xdbl, 64, nullptr, nullptr, nullptr, nullptr);
    // dt (both dirs): M=8192, N=1024, K=32; W+bias switch at m=4096
    gemm_k<EPI_F16_SOFTPLUS, 64, 64, 32><<<dim3(128, 16), blk, 0, stream>>>(
        xdbl, xdbl, dt_wb + (size_t)(2 * il) * DI_ * DTR_,
        dt_wb + (size_t)(2 * il + 1) * DI_ * DTR_, NOSPLIT, M_,
        DI_, DTR_, 64, DTR_,
        nullptr, (short*)dtb, DI_, m_dt_b + (size_t)(2 * il) * DI_,
        nullptr, nullptr, nullptr);
    // fused scans, LDS-staged: grid (256,16) = 4096 blocks
    const float* Alog = m_A_log + (size_t)(2 * il) * DI_ * DS_;
    const float* Dp = m_D + (size_t)(2 * il) * DI_;
    scan_p1<<<dim3(256, CH_), blk, 0, stream>>>(dtb, xc, xdbl, Alog, part_h, part_A);
    scan_p2<<<dim3(1024), blk, 0, stream>>>(part_h, part_A);
    scan_p3<<<dim3(256, CH_), blk, 0, stream>>>(dtb, xc, xdbl, zbuf, Alog, Dp, part_h);
    // out-proj (concat-K over y0|y1); A1 rows un-reversed via REVA=1
    gemm_k<EPI_HALF_BF16, 64, 32, 64, 1><<<dim3(64, 16), blk, 0, stream>>>(
        (const short*)dtb, (const short*)(dtb + (size_t)M_ * DI_),
        out_wb + (size_t)(2 * il) * DM_ * DI_,
        out_wb + (size_t)(2 * il + 1) * DM_ * DI_,
        DI_, NOSPLIT, DM_, 2 * DI_, DI_, DI_,
        nullptr, vtmp, DM_, nullptr, nullptr, nullptr, nullptr);
    ln_k<1><<<dim3(4096), blk, 0, stream>>>(h, vtmp, nullptr,
        ffn_ln_g + il * DM_, ffn_ln_b + il * DM_, hn);
    // ffn1: N=2048, K=512 -> f1out [M][2048]
    gemm_k<EPI_GELU, 64, 128, 32><<<dim3(64, 16), blk, 0, stream>>>(
        hn, hn, w1b + (size_t)il * 4 * DM_ * DM_,
        w1b + (size_t)il * 4 * DM_ * DM_, NOSPLIT, NOSPLIT,
        4 * DM_, DM_, DM_, DM_,
        nullptr, f1out, 4 * DM_, ffn_b1 + (size_t)il * 4 * DM_,
        nullptr, nullptr, nullptr);
    // ffn2: N=512, K=2048 -> ftmp
    gemm_k<EPI_BF16, 64, 32, 64><<<dim3(64, 16), blk, 0, stream>>>(
        f1out, f1out, w2b + (size_t)il * DM_ * 4 * DM_,
        w2b + (size_t)il * DM_ * 4 * DM_, NOSPLIT, NOSPLIT,
        DM_, 4 * DM_, 4 * DM_, 4 * DM_,
        nullptr, ftmp, DM_, nullptr, nullptr, nullptr, nullptr);
  }

  ln_k<2><<<dim3(4096), blk, 0, stream>>>(h, ftmp, ffn_b2 + 2 * DM_,
      enc_g, enc_b, hn);
  // proj: N=96, K=512
  gemm_k<EPI_PROJ, 64, 32, 64><<<dim3(64, 3), blk, 0, stream>>>(
      hn, hn, projb, projb, NOSPLIT, NOSPLIT, PL_, DM_, DM_, DM_,
      out, nullptr, 0, proj_b, xlast, stdevp, means);
}

// Round 18
// 923.836 us; speedup vs baseline: 1.0102x; 1.0102x over previous
//
#include <hip/hip_runtime.h>
#include <hip/hip_bf16.h>
#include <math.h>

#define B_ 8
#define L_ 512
#define DV_ 512
#define DM_ 512
#define PL_ 96
#define EL_ 3
#define DS_ 16
#define DC_ 4
#define DI_ 1024
#define DTR_ 32
#define S_ 512
#define M_ 4096        // B*S
#define CH_ 16         // scan chunks
#define CS_ 32         // steps per chunk
#define LOG2E_ 1.44269504088896f

typedef float f32x4 __attribute__((ext_vector_type(4)));
typedef short bf16x8 __attribute__((ext_vector_type(8)));
typedef short bf16x4 __attribute__((ext_vector_type(4)));

__device__ __forceinline__ float bf2f(short s) {
  unsigned u = ((unsigned)(unsigned short)s) << 16;
  return __builtin_bit_cast(float, u);
}
__device__ __forceinline__ short f2bf(float f) {
  unsigned u = __builtin_bit_cast(unsigned, f);
  u = u + 0x7FFFu + ((u >> 16) & 1u);   // RNE
  return (short)(u >> 16);
}
__device__ __forceinline__ float h2f(unsigned short u) {
  _Float16 h = __builtin_bit_cast(_Float16, u);
  return (float)h;
}
__device__ __forceinline__ unsigned short f2h(float f) {
  _Float16 h = (_Float16)f;
  return __builtin_bit_cast(unsigned short, h);
}

// Native v_exp_f32 (exp2).  NOT libm exp2f (denormal fixups — round-7
// regression).  Fallback keeps correctness if the builtin is missing.
__device__ __forceinline__ float exp2n(float x) {
#if __has_builtin(__builtin_amdgcn_exp2f)
  return __builtin_amdgcn_exp2f(x);
#else
  return __expf(x * 0.69314718055994531f);
#endif
}

// global -> LDS DMA, 16B per lane.  LDS dest is wave-uniform base + lane*16.
__device__ __forceinline__ void gload16(const short* g, short* l) {
  __builtin_amdgcn_global_load_lds(
      (const __attribute__((address_space(1))) void*)g,
      (__attribute__((address_space(3))) void*)l, 16, 0, 0);
}

// ---------------------------------------------------------------------------
// One-shot fp32 -> bf16 conversion of ALL GEMM weights into workspace.
// ---------------------------------------------------------------------------
#define WC0 65536                 // emb_w      512*512
#define WC1 (WC0 + 1572864)       // m_in_w     6*2048*512
#define WC2 (WC1 + 98304)         // m_xp_w     6*64*1024
#define WC3 (WC2 + 49152)         // m_dt_w     6*1024*32
#define WC4 (WC3 + 786432)        // m_out_w    6*512*1024
#define WC5 (WC4 + 786432)        // ffn_w1     3*2048*512
#define WC6 (WC5 + 786432)        // ffn_w2     3*512*2048
#define WC7 (WC6 + 12288)        // proj_w     96*512
// WC7 = 4157440 float4s; grid = 16240 * 256 exactly.

__global__ __launch_bounds__(256)
void wcvt_k(const float* __restrict__ e, const float* __restrict__ iw,
            const float* __restrict__ xp, const float* __restrict__ dtw,
            const float* __restrict__ ow, const float* __restrict__ w1,
            const float* __restrict__ w2, const float* __restrict__ pw,
            short* __restrict__ de, short* __restrict__ di,
            short* __restrict__ dxp, short* __restrict__ ddt,
            short* __restrict__ dow, short* __restrict__ dw1,
            short* __restrict__ dw2, short* __restrict__ dpw)
{
  int idx = blockIdx.x * 256 + threadIdx.x;
  const float* s; short* d; int off;
  if (idx < WC0)      { s = e;   d = de;  off = idx; }
  else if (idx < WC1) { s = iw;  d = di;  off = idx - WC0; }
  else if (idx < WC2) { s = xp;  d = dxp; off = idx - WC1; }
  else if (idx < WC3) { s = dtw; d = ddt; off = idx - WC2; }
  else if (idx < WC4) { s = ow;  d = dow; off = idx - WC3; }
  else if (idx < WC5) { s = w1;  d = dw1; off = idx - WC4; }
  else if (idx < WC6) { s = w2;  d = dw2; off = idx - WC5; }
  else                { s = pw;  d = dpw; off = idx - WC6; }
  float4 v = ((const float4*)s)[off];
  union { short sh[4]; int2 p; } r;
  r.sh[0] = f2bf(v.x); r.sh[1] = f2bf(v.y);
  r.sh[2] = f2bf(v.z); r.sh[3] = f2bf(v.w);
  ((int2*)d)[off] = r.p;
}

// ---------------------------------------------------------------------------
// Instance-norm statistics, two-phase.
// ---------------------------------------------------------------------------
__global__ __launch_bounds__(256)
void stats1_k(const float* __restrict__ x, float* __restrict__ ps)
{
  int d = blockIdx.x * 256 + threadIdx.x;       // 0..511
  int b = blockIdx.y;
  int lc = blockIdx.z;                          // 16 chunks of 32
  const float* xp = x + ((size_t)b * L_ + lc * 32) * DV_ + d;
  float s = 0.f, ss = 0.f;
  #pragma unroll 8
  for (int l = 0; l < 32; l++) {
    float v = xp[(size_t)l * DV_];
    s += v; ss += v * v;
  }
  int o = (lc * B_ + b) * DV_ + d;
  ps[o] = s; ps[o + 16 * B_ * DV_] = ss;
}

__global__ __launch_bounds__(256)
void stats2_k(const float* __restrict__ x, const float* __restrict__ ps,
              float* __restrict__ means, float* __restrict__ stdev,
              float* __restrict__ rstd, float* __restrict__ xlast)
{
  int d = blockIdx.x * 256 + threadIdx.x;
  int b = blockIdx.y;
  float s = 0.f, ss = 0.f;
  #pragma unroll
  for (int lc = 0; lc < 16; lc++) {
    int o = (lc * B_ + b) * DV_ + d;
    s += ps[o]; ss += ps[o + 16 * B_ * DV_];
  }
  float mu = s / (float)L_;
  float var = ss / (float)L_ - mu * mu;
  float sd = sqrtf(var + 1e-5f);
  float rs = 1.f / sd;
  int idx = b * DV_ + d;
  means[idx] = mu; stdev[idx] = sd; rstd[idx] = rs;
  xlast[idx] = (x[((size_t)b * L_ + L_ - 1) * DV_ + d] - mu) * rs;
}

// ---------------------------------------------------------------------------
// Normalize + transpose: xnT[b,d,l] = (x[b,l,d]-mu[b,d])*rstd[b,d]  (bf16)
// ---------------------------------------------------------------------------
__global__ __launch_bounds__(256)
void tnorm_k(const float* __restrict__ x, const float* __restrict__ means,
             const float* __restrict__ rstd, short* __restrict__ xnT)
{
  __shared__ float tile[64][65];
  const int t = threadIdx.x;
  const int j = t & 63;
  const int i0 = t >> 6;                 // 0..3
  const int bz = blockIdx.z;
  const int l0 = blockIdx.y << 6;
  const int d0 = blockIdx.x << 6;
  const float* xp = x + ((size_t)bz * L_ + l0) * DV_ + d0;
  #pragma unroll
  for (int i = i0; i < 64; i += 4) tile[i][j] = xp[(size_t)i * DV_ + j];
  __syncthreads();
  short* op = xnT + ((size_t)bz * DV_ + d0) * L_ + l0;
  const int sb = bz * DV_ + d0;
  #pragma unroll
  for (int i = i0; i < 64; i += 4) {
    float mu = means[sb + i];
    float rs = rstd[sb + i];
    op[(size_t)i * L_ + j] = f2bf((tile[j][i] - mu) * rs);
  }
}

// ---------------------------------------------------------------------------
// Fused LayerNorm: optionally h += add (+ abias) in place, then LN -> bf16.
// ---------------------------------------------------------------------------
template <int ADD>
__global__ __launch_bounds__(256)
void ln_k(float* __restrict__ X, const short* __restrict__ add,
          const float* __restrict__ abias,
          const float* __restrict__ g, const float* __restrict__ b,
          short* __restrict__ Y)
{
  int row = blockIdx.x;
  float* x = X + (size_t)row * DM_;
  int t = threadIdx.x;
  float v0 = x[t], v1 = x[t + 256];
  if constexpr (ADD >= 1) {
    v0 += bf2f(add[(size_t)row * DM_ + t]);
    v1 += bf2f(add[(size_t)row * DM_ + t + 256]);
    if constexpr (ADD == 2) { v0 += abias[t]; v1 += abias[t + 256]; }
    x[t] = v0; x[t + 256] = v1;
  }
  float s = v0 + v1, ss = v0 * v0 + v1 * v1;
  #pragma unroll
  for (int o = 1; o < 64; o <<= 1) { s += __shfl_xor(s, o); ss += __shfl_xor(ss, o); }
  __shared__ float sb[8];
  int wave = t >> 6, lane = t & 63;
  if (lane == 0) { sb[wave] = s; sb[4 + wave] = ss; }
  __syncthreads();
  s = sb[0] + sb[1] + sb[2] + sb[3];
  ss = sb[4] + sb[5] + sb[6] + sb[7];
  float mu = s / (float)DM_;
  float var = ss / (float)DM_ - mu * mu;
  float rs = rsqrtf(var + 1e-5f);
  Y[(size_t)row * DM_ + t]       = f2bf((v0 - mu) * rs * g[t]       + b[t]);
  Y[(size_t)row * DM_ + t + 256] = f2bf((v1 - mu) * rs * g[t + 256] + b[t + 256]);
}

// ---------------------------------------------------------------------------
// Depthwise causal conv, BOTH DIRS in one dispatch.  Vectorized, 8 ch/thread.
// ---------------------------------------------------------------------------
__global__ __launch_bounds__(256)
void conv2_k(const short* __restrict__ xcin, const float* __restrict__ w0,
             const float* __restrict__ w1, const float* __restrict__ cb0,
             const float* __restrict__ cb1, short* __restrict__ xcout)
{
  int idx = blockIdx.x * 256 + threadIdx.x;   // over 2*B*S*DI/8 = 2^20
  int dir = idx >> 19;
  int id2 = idx & ((1 << 19) - 1);
  int ig = (id2 & 127) << 3;                  // channel group base
  int bs = id2 >> 7;                          // b*S + tau
  int tt0 = bs & (S_ - 1);
  int b = bs >> 9;
  const float* w  = dir ? w1  : w0;
  const float* cb = dir ? cb1 : cb0;
  const short* u = xcin + (size_t)dir * M_ * DI_ + (size_t)(b * S_) * DI_ + ig;
  float4 wv[8];
  #pragma unroll
  for (int n = 0; n < 8; n++) wv[n] = *(const float4*)(w + (ig + n) * DC_);
  float acc[8];
  {
    float4 c0 = *(const float4*)(cb + ig);
    float4 c1 = *(const float4*)(cb + ig + 4);
    acc[0] = c0.x; acc[1] = c0.y; acc[2] = c0.z; acc[3] = c0.w;
    acc[4] = c1.x; acc[5] = c1.y; acc[6] = c1.z; acc[7] = c1.w;
  }
  #pragma unroll
  for (int k = 0; k < DC_; k++) {
    int tt = tt0 - (DC_ - 1) + k;
    if (tt >= 0) {
      bf16x8 uv = *(const bf16x8*)(u + (size_t)tt * DI_);
      #pragma unroll
      for (int n = 0; n < 8; n++) {
        float wk = (k == 0) ? wv[n].x : (k == 1) ? wv[n].y
                 : (k == 2) ? wv[n].z : wv[n].w;
        acc[n] += wk * bf2f(uv[n]);
      }
    }
  }
  union { short sh[8]; bf16x8 v; } r;
  #pragma unroll
  for (int n = 0; n < 8; n++) {
    float sig = 1.f / (1.f + __expf(-acc[n]));
    r.sh[n] = f2bf(acc[n] * sig);
  }
  *(bf16x8*)(xcout + (size_t)dir * M_ * DI_ + ((size_t)bs << 10) + ig) = r.v;
}

// ---------------------------------------------------------------------------
// Chunked selective scan, both dirs fused, forward-only, LDS-staged,
// B/C pre-converted to fp32 in LDS (round-15 proven config — unchanged).
// ---------------------------------------------------------------------------
__global__ __launch_bounds__(256)
void scan_p1(const unsigned short* __restrict__ dt16, const short* __restrict__ xc,
             const short* __restrict__ xdbl, const float* __restrict__ A_log,
             unsigned short* __restrict__ part_h, unsigned short* __restrict__ part_A)
{
  __shared__ short ldt[CS_ * 64];   // [32][64] fp16 dt
  __shared__ short lu [CS_ * 64];   // [32][64] bf16 u
  __shared__ short lb [CS_ * 16];   // [32][16] bf16 B (staging)
  __shared__ __align__(16) float lbf[CS_ * 16];   // [32][16] fp32 B
  const int tid = threadIdx.x;
  const int bid = blockIdx.x;                 // 0..255
  const int c = blockIdx.y;
  const int q = tid & 3;
  const int il = tid >> 2;                    // 0..63
  const int i = ((bid & 15) << 6) + il;
  const int b = (bid >> 4) & (B_ - 1);
  const int dir = bid >> 7;

  {  // stage: dt,u rows [32][64] (16B/thread each); B rows [32][16] (wave 0)
    const int srow = tid >> 3, scol = (tid & 7) << 3;
    const size_t g = (size_t)dir * M_ * DI_ +
                     ((size_t)b * S_ + c * CS_ + srow) * DI_ + ((bid & 15) << 6) + scol;
    const int wb = (tid >> 6) << 9;           // wave*512 shorts
    gload16((const short*)dt16 + g, &ldt[wb]);
    gload16(xc + g, &lu[wb]);
    if (tid < 64) {
      const int brow = tid >> 1, bcol = (tid & 1) << 3;
      const size_t gb = (size_t)dir * M_ * 64 +
                        ((size_t)b * S_ + c * CS_ + brow) * 64 + DTR_ + bcol;
      gload16(xdbl + gb, &lb[0]);
    }
  }
  asm volatile("s_waitcnt vmcnt(0)" ::: "memory");
  __builtin_amdgcn_s_barrier();
  // one-shot B convert: 512 values, 2/thread
  lbf[tid] = bf2f(lb[tid]);
  lbf[tid + 256] = bf2f(lb[tid + 256]);
  __syncthreads();

  float Ai2[4];
  const float* al = A_log + (size_t)dir * DI_ * DS_ + i * DS_ + q * 4;
  #pragma unroll
  for (int n = 0; n < 4; n++) Ai2[n] = -__expf(al[n]) * LOG2E_;

  float h[4];
  #pragma unroll
  for (int n = 0; n < 4; n++) h[n] = 0.f;
  float dsum = 0.f;

  const unsigned short* pdt = (const unsigned short*)ldt + il;
  const short* pu = lu + il;
  const float* pb = lbf + q * 4;
  for (int s0 = 0; s0 < CS_; s0 += 8) {
    #pragma unroll
    for (int k = 0; k < 8; k++) {
      float dtv = h2f(pdt[k * 64]);
      float u = bf2f(pu[k * 64]);
      f32x4 vB = *(const f32x4*)(pb + k * 16);
      float du = dtv * u;
      dsum += dtv;
      #pragma unroll
      for (int n = 0; n < 4; n++) {
        float dA = exp2n(dtv * Ai2[n]);
        h[n] = dA * h[n] + du * vB[n];
      }
    }
    pdt += 512; pu += 512; pb += 128;
  }
  union { unsigned short s[4]; int2 v; } uh, ua;
  #pragma unroll
  for (int n = 0; n < 4; n++) {
    uh.s[n] = f2h(h[n]);
    ua.s[n] = f2h(exp2n(Ai2[n] * dsum));   // exact: prod exp(dt*A)=exp(A*sum dt)
  }
  const size_t ix = ((((size_t)c * 2 * B_ + dir * B_ + b) * DI_ + i) << 4) + (q << 2);
  *(int2*)(part_h + ix) = uh.v;
  *(int2*)(part_A + ix) = ua.v;
}

__global__ __launch_bounds__(256)
void scan_p2(unsigned short* __restrict__ part_h,
             const unsigned short* __restrict__ part_A)
{
  const size_t gid = (size_t)blockIdx.x * 256 + threadIdx.x;   // 2*B*DI*DS
  const size_t stride = (size_t)2 * B_ * DI_ * DS_;
  float hin = 0.f;
  #pragma unroll
  for (int c = 0; c < CH_; c++) {
    size_t ix = (size_t)c * stride + gid;
    float hh = h2f(part_h[ix]);
    float pA = h2f(part_A[ix]);
    part_h[ix] = f2h(hin);            // becomes chunk c's incoming state
    hin = hh + pA * hin;
  }
}

// y overwrites dt16 in place; reads come from the LDS snapshot staged
// before any store, so there is no RAW hazard at all.
__global__ __launch_bounds__(256)
void scan_p3(unsigned short* dt16, const short* __restrict__ xc,
             const short* __restrict__ xdbl, const short* __restrict__ zb,
             const float* __restrict__ A_log, const float* __restrict__ Dp,
             const unsigned short* __restrict__ part_h)
{
  __shared__ short ldt[CS_ * 64];   // [32][64] fp16 dt
  __shared__ short lu [CS_ * 64];   // [32][64] bf16 u
  __shared__ short lz [CS_ * 64];   // [32][64] bf16 silu(z)
  __shared__ short lbc[CS_ * 32];   // [32][32] bf16 B|C (staging)
  __shared__ __align__(16) float lbcf[CS_ * 32];  // [32][32] fp32 B|C
  const int tid = threadIdx.x;
  const int bid = blockIdx.x;
  const int c = blockIdx.y;
  const int q = tid & 3;
  const int il = tid >> 2;
  const int i = ((bid & 15) << 6) + il;
  const int b = (bid >> 4) & (B_ - 1);
  const int dir = bid >> 7;

  const size_t base = (size_t)dir * M_ * DI_ +
                      ((size_t)b * S_ + c * CS_) * DI_ + ((bid & 15) << 6);
  {  // stage: dt,u,z rows [32][64]; B|C rows [32][32] (waves 0-1)
    const int srow = tid >> 3, scol = (tid & 7) << 3;
    const size_t g = base + (size_t)srow * DI_ + scol;
    const int wb = (tid >> 6) << 9;
    gload16((const short*)dt16 + g, &ldt[wb]);
    gload16(xc + g, &lu[wb]);
    gload16(zb + g, &lz[wb]);
    if (tid < 128) {
      const int brow = tid >> 2, bcol = (tid & 3) << 3;
      const size_t gb = (size_t)dir * M_ * 64 +
                        ((size_t)b * S_ + c * CS_ + brow) * 64 + DTR_ + bcol;
      gload16(xdbl + gb, &lbc[(tid >> 6) << 9]);
    }
  }
  asm volatile("s_waitcnt vmcnt(0)" ::: "memory");
  __builtin_amdgcn_s_barrier();
  // one-shot B|C convert: 1024 values, 4/thread
  #pragma unroll
  for (int p = 0; p < 4; p++)
    lbcf[p * 256 + tid] = bf2f(lbc[p * 256 + tid]);
  __syncthreads();

  float Ai2[4];
  const float* al = A_log + (size_t)dir * DI_ * DS_ + i * DS_ + q * 4;
  #pragma unroll
  for (int n = 0; n < 4; n++) Ai2[n] = -__expf(al[n]) * LOG2E_;
  const float Di = Dp[(size_t)dir * DI_ + i];

  float h[4];
  {
    const size_t ix = ((((size_t)c * 2 * B_ + dir * B_ + b) * DI_ + i) << 4) + (q << 2);
    union { unsigned short s[4]; int2 v; } uh;
    uh.v = *(const int2*)(part_h + ix);
    #pragma unroll
    for (int n = 0; n < 4; n++) h[n] = h2f(uh.s[n]);
  }

  const unsigned short* pdt = (const unsigned short*)ldt + il;
  const short* pu = lu + il;
  const short* pz = lz + il;
  const float* pbc = lbcf + q * 4;
  short* py = (short*)dt16 + base + il;       // y over dt (global)

  for (int s0 = 0; s0 < CS_; s0 += 4) {
    #pragma unroll
    for (int k = 0; k < 4; k++) {
      float dtv = h2f(pdt[k * 64]);
      float u = bf2f(pu[k * 64]);
      float sil = bf2f(pz[k * 64]);
      f32x4 vB = *(const f32x4*)(pbc + k * 32);
      f32x4 vC = *(const f32x4*)(pbc + k * 32 + 16);
      float du = dtv * u;
      float yp = 0.f;
      #pragma unroll
      for (int n = 0; n < 4; n++) {
        float dA = exp2n(dtv * Ai2[n]);
        h[n] = dA * h[n] + du * vB[n];
        yp += h[n] * vC[n];
      }
      yp += __shfl_xor(yp, 1);
      yp += __shfl_xor(yp, 2);          // quad-wide sum over all 16 states
      float yv = (yp + u * Di) * sil;
      if (q == 0) py[(size_t)k * DI_] = f2bf(yv);
    }
    pdt += 256; pu += 256; pz += 256; pbc += 128; py += 4 * DI_;
  }
}

// ---------------------------------------------------------------------------
// bf16 MFMA GEMM.  Round 18: prefetch depth is now a template param NB
// (LDS buffer count; depth D = NB-1).  The BK=32 class (in-proj2/ffn1/dt)
// uses NB=2: LDS 36->24 KB (16 KB for dt) lifts residency 4->6 (8) blocks/CU.
// Round-17 PMC showed that class latency/occupancy-bound (Occ 32%,
// MfmaUtil 15%) with conflicts already at 0 — depth-2 prefetch was paying
// LDS for latency cover that TLP supplies more cheaply at BK=32.
// BK=64 class keeps NB=3 (proven config, byte-identical).
// Pair-row XOR swizzle (round 17) retained everywhere.
// ---------------------------------------------------------------------------
enum { EPI_F32_BIAS, EPI_BF16, EPI_F16_SOFTPLUS, EPI_HALF_BF16, EPI_GELU,
       EPI_PROJ, EPI_INPROJ2 };

template <int EPI, int BM, int BN, int BK, int REVA = 0, int NB = 3>
__global__ __launch_bounds__(256)
void gemm_k(const short* __restrict__ A0, const short* __restrict__ A1,
            const short* __restrict__ W0, const short* __restrict__ W1,
            int khalf, int mhalf, int N, int K, int lda, int ldw,
            float* __restrict__ Cf, short* __restrict__ Cb, int ldc,
            const float* __restrict__ bias,
            const float* __restrict__ xlast, const float* __restrict__ stdev,
            const float* __restrict__ means)
{
  constexpr int MT = BM / 32;
  constexpr int NT = BN / 32;
  constexpr int KS = BK / 32;
  constexpr int CHK = BK / 8;
  constexpr int MSK = CHK - 1;
  constexpr int NA = (BM * CHK) / 256;
  constexpr int NW = (BN * CHK) / 256;
  constexpr int VC = NA + NW;
  constexpr int D = NB - 1;             // prefetch depth
  __shared__ __align__(16) short As[NB][BM * BK];
  __shared__ __align__(16) short Ws[NB][BN * BK];
  const int tid = threadIdx.x;
  const int m0 = blockIdx.x * BM;
  const int n0 = blockIdx.y * BN;
  const int wave = tid >> 6, lane = tid & 63;
  const int wm = (wave & 1) * (BM / 2), wn = (wave >> 1) * (BN / 2);
  const int quad = lane >> 4, l16 = lane & 15;

  const short* W0m = (m0 < mhalf) ? W0 : W1;   // block-uniform M-half switch

  f32x4 acc[MT][NT] = {};

  size_t aoff[NA], aoffR[REVA ? NA : 1];
  #pragma unroll
  for (int j = 0; j < NA; j++) {
    int id = j * 256 + tid;
    int r = id / CHK, qp = id % CHK;
    aoff[j] = (size_t)(m0 + r) * lda + ((qp ^ ((r >> 1) & MSK)) << 3);
    if constexpr (REVA)
      aoffR[j] = (size_t)((m0 + r) ^ (S_ - 1)) * lda + ((qp ^ ((r >> 1) & MSK)) << 3);
  }
  size_t woff[NW];
  #pragma unroll
  for (int j = 0; j < NW; j++) {
    int id = j * 256 + tid;
    int r = id / CHK, qp = id % CHK;
    int wr = n0 + r; if (wr > N - 1) wr = N - 1;
    woff[j] = (size_t)wr * ldw + ((qp ^ ((r >> 1) & MSK)) << 3);
  }
  const int lbase = wave * 512;

  const int KB = K / BK;

  auto stage = [&](int slab, int bi) {
    const int k0 = slab * BK;
    const short* Ab = (k0 < khalf) ? A0 + k0 : A1 + (k0 - khalf);
    const short* Wb = (k0 < khalf) ? W0m + k0 : W1 + (k0 - khalf);
    const size_t* ao = (REVA && k0 >= khalf) ? aoffR : aoff;
    #pragma unroll
    for (int j = 0; j < NA; j++)
      gload16(Ab + ao[j], &As[bi][j * 2048 + lbase]);
    #pragma unroll
    for (int j = 0; j < NW; j++)
      gload16(Wb + woff[j], &Ws[bi][j * 2048 + lbase]);
  };

  // prologue: stage slabs 0..D-1 into bufs 0..D-1; wait slab 0; barrier.
  stage(0, 0);
  if (D > 1 && KB > 1) stage(1, 1);
  __builtin_amdgcn_sched_barrier(0);
  if constexpr (D == 1) {
    asm volatile("s_waitcnt vmcnt(0)" ::: "memory");
  } else {
    if (KB > 1) asm volatile("s_waitcnt vmcnt(%0)" :: "n"(VC) : "memory");
    else        asm volatile("s_waitcnt vmcnt(0)" ::: "memory");
  }
  __builtin_amdgcn_s_barrier();
  __builtin_amdgcn_sched_barrier(0);

  int cur = 0, nxt = D % NB;
  for (int kb = 0; kb < KB; kb++) {
    if (kb + D < KB) {
      stage(kb + D, nxt);
      __builtin_amdgcn_sched_barrier(0);
    }
    bf16x8 af[MT][KS], bfr[NT][KS];
    #pragma unroll
    for (int mt = 0; mt < MT; mt++)
      #pragma unroll
      for (int st = 0; st < KS; st++)
        af[mt][st] = *(const bf16x8*)(&As[cur][0] + (wm + mt * 16 + l16) * BK +
                                      (((st * 4 + quad) ^ ((l16 >> 1) & MSK)) << 3));
    #pragma unroll
    for (int nt = 0; nt < NT; nt++)
      #pragma unroll
      for (int st = 0; st < KS; st++)
        bfr[nt][st] = *(const bf16x8*)(&Ws[cur][0] + (wn + nt * 16 + l16) * BK +
                                       (((st * 4 + quad) ^ ((l16 >> 1) & MSK)) << 3));
    #pragma unroll
    for (int st = 0; st < KS; st++)
      #pragma unroll
      for (int mt = 0; mt < MT; mt++)
        #pragma unroll
        for (int nt = 0; nt < NT; nt++)
          acc[mt][nt] = __builtin_amdgcn_mfma_f32_16x16x32_bf16(
              af[mt][st], bfr[nt][st], acc[mt][nt], 0, 0, 0);
    if (kb + 1 < KB) {
      __builtin_amdgcn_sched_barrier(0);
      // need slab kb+1 done; deeper in-flight slabs may stay in flight.
      if constexpr (D == 1) {
        asm volatile("s_waitcnt vmcnt(0)" ::: "memory");
      } else {
        if (kb + D < KB) asm volatile("s_waitcnt vmcnt(%0)" :: "n"(VC) : "memory");
        else             asm volatile("s_waitcnt vmcnt(0)" ::: "memory");
      }
      __builtin_amdgcn_s_barrier();
      __builtin_amdgcn_sched_barrier(0);
      cur = (cur == NB - 1) ? 0 : cur + 1;
      nxt = (nxt == NB - 1) ? 0 : nxt + 1;
    }
  }

  const int boff = (m0 < mhalf) ? 0 : N;   // M-half bias switch (contiguous)

  #pragma unroll
  for (int mt = 0; mt < MT; mt++) {
    #pragma unroll
    for (int nt = 0; nt < NT; nt++) {
      int n = n0 + wn + nt * 16 + l16;
      if (n >= N) continue;
      #pragma unroll
      for (int r = 0; r < 4; r++) {
        int m = m0 + wm + mt * 16 + quad * 4 + r;
        float v = acc[mt][nt][r];
        if constexpr (EPI == EPI_F32_BIAS) {
          Cf[(size_t)m * ldc + n] = v + bias[n];
        } else if constexpr (EPI == EPI_BF16) {
          Cb[(size_t)m * ldc + n] = f2bf(v);
        } else if constexpr (EPI == EPI_F16_SOFTPLUS) {
          float tt = v + bias[n + boff];
          float sp = (tt > 20.f) ? tt : log1pf(__expf(tt));
          ((unsigned short*)Cb)[(size_t)m * ldc + n] = f2h(sp);
        } else if constexpr (EPI == EPI_HALF_BF16) {
          Cb[(size_t)m * ldc + n] = f2bf(0.5f * v);
        } else if constexpr (EPI == EPI_GELU) {
          float tt = v + bias[n];
          Cb[(size_t)m * ldc + n] = f2bf(0.5f * tt * (1.f + erff(tt * 0.70710678118f)));
        } else if constexpr (EPI == EPI_PROJ) {
          int bb = m >> 9, d = m & 511;
          float tt = v + bias[n] + xlast[m];
          tt = tt * stdev[m] + means[m];
          Cf[((size_t)bb * PL_ + n) * DV_ + d] = tt;
        } else if constexpr (EPI == EPI_INPROJ2) {
          // fused 2-dir in-proj: dir = n>>11; dir1 rows stored reversed.
          int d2 = n >> 11, nn = n & 2047;
          int mm = d2 ? (m ^ (S_ - 1)) : m;
          short* sc2 = Cb + (size_t)d2 * M_ * DI_;
          short* zb2 = (short*)Cf + (size_t)d2 * M_ * DI_;
          if (nn < DI_) sc2[(size_t)mm * DI_ + nn] = f2bf(v);
          else {
            float sz = v / (1.f + __expf(-v));     // pre-apply silu to z
            zb2[(size_t)mm * DI_ + (nn - DI_)] = f2bf(sz);
          }
        }
      }
    }
  }
}

// ---------------------------------------------------------------------------
extern "C" void kernel_launch(void* const* d_in, const int* in_sizes, int n_in,
                              void* d_out, int out_size, void* d_ws, size_t ws_size,
                              hipStream_t stream)
{
  (void)in_sizes; (void)n_in; (void)out_size; (void)ws_size;
  const float* x        = (const float*)d_in[0];
  const float* emb_w    = (const float*)d_in[1];
  const float* emb_b    = (const float*)d_in[2];
  const float* ln_g     = (const float*)d_in[3];
  const float* ln_b     = (const float*)d_in[4];
  const float* m_in_w   = (const float*)d_in[5];
  const float* m_conv_w = (const float*)d_in[6];
  const float* m_conv_b = (const float*)d_in[7];
  const float* m_xp_w   = (const float*)d_in[8];
  const float* m_dt_w   = (const float*)d_in[9];
  const float* m_dt_b   = (const float*)d_in[10];
  const float* m_A_log  = (const float*)d_in[11];
  const float* m_D      = (const float*)d_in[12];
  const float* m_out_w  = (const float*)d_in[13];
  const float* ffn_ln_g = (const float*)d_in[14];
  const float* ffn_ln_b = (const float*)d_in[15];
  const float* ffn_w1   = (const float*)d_in[16];
  const float* ffn_b1   = (const float*)d_in[17];
  const float* ffn_w2   = (const float*)d_in[18];
  const float* ffn_b2   = (const float*)d_in[19];
  const float* enc_g    = (const float*)d_in[20];
  const float* enc_b    = (const float*)d_in[21];
  const float* proj_w   = (const float*)d_in[22];
  const float* proj_b   = (const float*)d_in[23];
  float* out = (float*)d_out;

  char* ws = (char*)d_ws;
  const size_t MB = 1024 * 1024;
  // Layout (high-water 128 MB):
  //  0-8   h | 8-12 hn | 12-16 ftmp/vtmp | 16-24 part_h (scan window)
  //  8-16  part_A alias | 24-40 zbuf/xnT/f1out | 40-56 xc | 56-72 dtb (y in
  //  place) | 72-73 xdbl | 73 stats(+partials) | 80-112 bf16 weight pool |
  //  112-128 conv scratch [2][M][DI]
  float* h      = (float*)(ws + 0);
  short* hn     = (short*)(ws + 8 * MB);
  short* ftmp   = (short*)(ws + 12 * MB);
  short* vtmp   = ftmp;
  short* zbuf   = (short*)(ws + 24 * MB);
  short* xnT    = zbuf;
  short* f1out  = zbuf;
  short* xc     = (short*)(ws + 40 * MB);
  unsigned short* dtb = (unsigned short*)(ws + 56 * MB);
  short* xdbl   = (short*)(ws + 72 * MB);
  float* stats  = (float*)(ws + 73 * MB);
  unsigned short* part_A = (unsigned short*)(ws + 8 * MB);
  unsigned short* part_h = (unsigned short*)(ws + 16 * MB);
  short* scratch= (short*)(ws + 112 * MB);   // [2][M][DI] conv input
  float* means = stats, *stdevp = stats + 4096, *rstd = stats + 8192, *xlast = stats + 12288;
  float* pstat = stats + 16384;              // 16x8x512 x2 partials (512KB)

  short* emb_wb = (short*)(ws + 80 * MB);
  short* in_wb  = emb_wb + 262144;      // 6 x 2048x512
  short* xp_wb  = in_wb  + 6291456;     // 6 x 64x1024
  short* dt_wb  = xp_wb  + 393216;      // 6 x 1024x32
  short* out_wb = dt_wb  + 196608;      // 6 x 512x1024
  short* w1b    = out_wb + 3145728;     // 3 x 2048x512
  short* w2b    = w1b    + 3145728;     // 3 x 512x2048
  short* projb  = w2b    + 3145728;     // 96x512

  dim3 blk(256);
  const int NOSPLIT = 1 << 30;

  wcvt_k<<<dim3(16240), blk, 0, stream>>>(
      emb_w, m_in_w, m_xp_w, m_dt_w, m_out_w, ffn_w1, ffn_w2, proj_w,
      emb_wb, in_wb, xp_wb, dt_wb, out_wb, w1b, w2b, projb);

  stats1_k<<<dim3(2, B_, 16), blk, 0, stream>>>(x, pstat);
  stats2_k<<<dim3(2, B_), blk, 0, stream>>>(x, pstat, means, stdevp, rstd, xlast);
  tnorm_k<<<dim3(8, 8, B_), blk, 0, stream>>>(x, means, rstd, xnT);
  // emb: M=4096, N=512, K=512
  gemm_k<EPI_F32_BIAS, 64, 32, 64><<<dim3(64, 16), blk, 0, stream>>>(
      xnT, xnT, emb_wb, emb_wb, NOSPLIT, NOSPLIT, DM_, L_, L_, L_,
      h, nullptr, DM_, emb_b, nullptr, nullptr, nullptr);

  for (int il = 0; il < EL_; il++) {
    if (il == 0)
      ln_k<0><<<dim3(4096), blk, 0, stream>>>(h, nullptr, nullptr, ln_g, ln_b, hn);
    else
      ln_k<2><<<dim3(4096), blk, 0, stream>>>(h, ftmp, ffn_b2 + (il - 1) * DM_,
          ln_g + il * DM_, ln_b + il * DM_, hn);
    // in-proj BOTH DIRS fused: N=4096, K=512 — grid (64, 32), NB=2 (24KB LDS)
    gemm_k<EPI_INPROJ2, 64, 128, 32, 0, 2><<<dim3(64, 32), blk, 0, stream>>>(
        hn, hn, in_wb + (size_t)(2 * il) * 2 * DI_ * DM_,
        in_wb + (size_t)(2 * il) * 2 * DI_ * DM_, NOSPLIT, NOSPLIT,
        4 * DI_, DM_, DM_, DM_,
        (float*)zbuf, scratch, DI_, nullptr, nullptr, nullptr, nullptr);
    // conv BOTH DIRS fused: grid 4096
    conv2_k<<<dim3(4096), blk, 0, stream>>>(
        scratch, m_conv_w + (size_t)(2 * il) * DI_ * DC_,
        m_conv_w + (size_t)(2 * il + 1) * DI_ * DC_,
        m_conv_b + (size_t)(2 * il) * DI_,
        m_conv_b + (size_t)(2 * il + 1) * DI_, xc);
    // xdbl (both dirs): M=8192, N=64, K=1024; W switches at m=4096
    gemm_k<EPI_BF16, 32, 32, 64><<<dim3(256, 2), blk, 0, stream>>>(
        xc, xc, xp_wb + (size_t)(2 * il) * 64 * DI_,
        xp_wb + (size_t)(2 * il + 1) * 64 * DI_, NOSPLIT, M_,
        64, DI_, DI_, DI_,
        nullptr, xdbl, 64, nullptr, nullptr, nullptr, nullptr);
    // dt (both dirs): M=8192, N=1024, K=32; W+bias switch at m=4096; NB=2
    gemm_k<EPI_F16_SOFTPLUS, 64, 64, 32, 0, 2><<<dim3(128, 16), blk, 0, stream>>>(
        xdbl, xdbl, dt_wb + (size_t)(2 * il) * DI_ * DTR_,
        dt_wb + (size_t)(2 * il + 1) * DI_ * DTR_, NOSPLIT, M_,
        DI_, DTR_, 64, DTR_,
        nullptr, (short*)dtb, DI_, m_dt_b + (size_t)(2 * il) * DI_,
        nullptr, nullptr, nullptr);
    // fused scans, LDS-staged: grid (256,16) = 4096 blocks
    const float* Alog = m_A_log + (size_t)(2 * il) * DI_ * DS_;
    const float* Dp = m_D + (size_t)(2 * il) * DI_;
    scan_p1<<<dim3(256, CH_), blk, 0, stream>>>(dtb, xc, xdbl, Alog, part_h, part_A);
    scan_p2<<<dim3(1024), blk, 0, stream>>>(part_h, part_A);
    scan_p3<<<dim3(256, CH_), blk, 0, stream>>>(dtb, xc, xdbl, zbuf, Alog, Dp, part_h);
    // out-proj (concat-K over y0|y1); A1 rows un-reversed via REVA=1
    gemm_k<EPI_HALF_BF16, 64, 32, 64, 1><<<dim3(64, 16), blk, 0, stream>>>(
        (const short*)dtb, (const short*)(dtb + (size_t)M_ * DI_),
        out_wb + (size_t)(2 * il) * DM_ * DI_,
        out_wb + (size_t)(2 * il + 1) * DM_ * DI_,
        DI_, NOSPLIT, DM_, 2 * DI_, DI_, DI_,
        nullptr, vtmp, DM_, nullptr, nullptr, nullptr, nullptr);
    ln_k<1><<<dim3(4096), blk, 0, stream>>>(h, vtmp, nullptr,
        ffn_ln_g + il * DM_, ffn_ln_b + il * DM_, hn);
    // ffn1: N=2048, K=512 -> f1out [M][2048]; NB=2
    gemm_k<EPI_GELU, 64, 128, 32, 0, 2><<<dim3(64, 16), blk, 0, stream>>>(
        hn, hn, w1b + (size_t)il * 4 * DM_ * DM_,
        w1b + (size_t)il * 4 * DM_ * DM_, NOSPLIT, NOSPLIT,
        4 * DM_, DM_, DM_, DM_,
        nullptr, f1out, 4 * DM_, ffn_b1 + (size_t)il * 4 * DM_,
        nullptr, nullptr, nullptr);
    // ffn2: N=512, K=2048 -> ftmp
    gemm_k<EPI_BF16, 64, 32, 64><<<dim3(64, 16), blk, 0, stream>>>(
        f1out, f1out, w2b + (size_t)il * DM_ * 4 * DM_,
        w2b + (size_t)il * DM_ * 4 * DM_, NOSPLIT, NOSPLIT,
        DM_, 4 * DM_, 4 * DM_, 4 * DM_,
        nullptr, ftmp, DM_, nullptr, nullptr, nullptr, nullptr);
  }

  ln_k<2><<<dim3(4096), blk, 0, stream>>>(h, ftmp, ffn_b2 + 2 * DM_,
      enc_g, enc_b, hn);
  // proj: N=96, K=512
  gemm_k<EPI_PROJ, 64, 32, 64><<<dim3(64, 3), blk, 0, stream>>>(
      hn, hn, projb, projb, NOSPLIT, NOSPLIT, PL_, DM_, DM_, DM_,
      out, nullptr, 0, proj_b, xlast, stdevp, means);
}